// Round 5
// baseline (604.021 us; speedup 1.0000x reference)
//
#include <hip/hip_runtime.h>
#include <cstdint>

// SparseMLP: out = relu(relu(x@W1^T+b1)@W2^T+b2)@W3^T+b3
// M = N = K = 4096 per layer. fp32 in/out; fp16 MFMA internally.
//
// R5 vs R4 (595us; GEMM 123us = 1117 TF, MfmaUtil 48%):
//  - True double-buffered K-loop (BK=64, 2x32KB LDS buffers, ONE barrier
//    per iter). Prefetch stage j+1 is issued AFTER the barrier into the
//    opposite buffer; the compiler's vmcnt(0)-before-s_barrier then waits
//    only on loads issued one full compute phase earlier (full slack),
//    instead of R4's zero-slack issue->drain->compute alternation.
//    Cost: 64KB LDS -> 2 blocks/CU. m132's 64KB failure kept the
//    zero-slack 2-barrier structure; this removes it.
//  - Converts identical to R4 (clean attribution of the GEMM change).

#define MATN 4096

typedef _Float16 half8 __attribute__((ext_vector_type(8)));
typedef float f32x4 __attribute__((ext_vector_type(4)));

// async global->LDS, 16B/lane. LDS dest = wave-uniform base + lane*16.
__device__ __forceinline__ void glds16(const void* g, void* l) {
    __builtin_amdgcn_global_load_lds(
        (const __attribute__((address_space(1))) char*)(uintptr_t)g,
        (__attribute__((address_space(3))) char*)(uintptr_t)l,
        16, 0, 0);
}

__device__ __forceinline__ void cvt_body(const float* __restrict__ in,
                                         _Float16* __restrict__ out, int n8) {
    for (int g = blockIdx.x * 256 + threadIdx.x; g < n8; g += gridDim.x * 256) {
        size_t i = (size_t)g * 8;
        float4 a = *(const float4*)(in + i);
        float4 b = *(const float4*)(in + i + 4);
        half8 o;
        o[0] = (_Float16)a.x; o[1] = (_Float16)a.y;
        o[2] = (_Float16)a.z; o[3] = (_Float16)a.w;
        o[4] = (_Float16)b.x; o[5] = (_Float16)b.y;
        o[6] = (_Float16)b.z; o[7] = (_Float16)b.w;
        *(half8*)(out + i) = o;
    }
}

__global__ __launch_bounds__(256)
void cvt_f16(const float* __restrict__ in, _Float16* __restrict__ out, int n8) {
    cvt_body(in, out, n8);
}

// two tensors in one launch (gridDim.y = 2)
__global__ __launch_bounds__(256)
void cvt_f16_2(const float* __restrict__ i0, _Float16* __restrict__ o0,
               const float* __restrict__ i1, _Float16* __restrict__ o1, int n8) {
    cvt_body(blockIdx.y ? i1 : i0, blockIdx.y ? o1 : o0, n8);
}

// C[m][n] = sum_k A[m][k]*B[n][k] + bias[n] (optional ReLU).
// A,B: [4096][4096] f16 row-major (K-contig). 128x128 tile, BK=64 dbuf,
// 2x2 waves x 4x4 MFMA(16x16x32) per wave, 2 k-halves per stage.
template <bool RELU, typename OutT>
__global__ __launch_bounds__(256, 2)
void gemm_bt(const _Float16* __restrict__ A, const _Float16* __restrict__ B,
             const float* __restrict__ bias, OutT* __restrict__ C) {
    __shared__ _Float16 sA[2][128 * 64];  // 2 x 16 KB, XOR-swizzled chunks
    __shared__ _Float16 sB[2][128 * 64];

    const int tid  = threadIdx.x;
    const int lane = tid & 63;
    const int w    = tid >> 6;   // 4 waves
    const int wm   = w >> 1;     // 2x2 wave grid over 128x128
    const int wn   = w & 1;
    const int l16  = lane & 15;
    const int kq   = lane >> 4;  // 0..3

    const int tileM = blockIdx.y * 128;
    const int tileN = blockIdx.x * 128;

    f32x4 acc[4][4] = {};

    // staging: thread t -> row_in = t>>3 (0..31), slot = t&7.
    // LDS slot s of row r holds global 16B chunk s ^ (r&7); thread t
    // fetches chunk (t&7)^(row_in&7). Rows advance 32/round (32%8==0).
    const int rin = tid >> 3;
    const int gch = (tid & 7) ^ (rin & 7);
    const _Float16* Ap = A + (size_t)(tileM + rin) * MATN + gch * 8;
    const _Float16* Bp = B + (size_t)(tileN + rin) * MATN + gch * 8;
    const size_t rstep = (size_t)32 * MATN;  // rows between staging rounds

    // fragment read offsets (khalf 0/1): row = wm*64+mi*16+l16 (row&7=l16&7),
    // wanted chunk = khalf*4+kq -> slot = (khalf*4+kq)^(l16&7).
    const int sl0 = kq ^ (l16 & 7);
    const int roffA = (wm * 64 + l16) * 64 + sl0 * 8;  // khalf1: ^4 -> +/-32
    const int roffB = (wn * 64 + l16) * 64 + sl0 * 8;
    const int x1 = ((sl0 ^ 4) - sl0) * 8;              // +32 or -32 elems

    // prologue: stage k-block 0 into buffer 0
    {
        char* da = (char*)sA[0] + w * 1024;
        char* db = (char*)sB[0] + w * 1024;
#pragma unroll
        for (int c = 0; c < 4; ++c) glds16(Ap + c * rstep, da + c * 4096);
#pragma unroll
        for (int c = 0; c < 4; ++c) glds16(Bp + c * rstep, db + c * 4096);
        Ap += 64; Bp += 64;
    }

    for (int j = 0; j < 64; ++j) {
        __syncthreads();  // vmcnt(0) here waits on PREV iter's prefetch only
        if (j < 63) {     // uniform branch: prefetch j+1 into opposite buf
            char* da = (char*)sA[(j + 1) & 1] + w * 1024;
            char* db = (char*)sB[(j + 1) & 1] + w * 1024;
#pragma unroll
            for (int c = 0; c < 4; ++c) glds16(Ap + c * rstep, da + c * 4096);
#pragma unroll
            for (int c = 0; c < 4; ++c) glds16(Bp + c * rstep, db + c * 4096);
            Ap += 64; Bp += 64;
        }

        const _Float16* cA = sA[j & 1] + roffA;
        const _Float16* cB = sB[j & 1] + roffB;
        half8 af[4], bf[4];
        // k-half 0
#pragma unroll
        for (int mi = 0; mi < 4; ++mi) af[mi] = *(const half8*)(cA + mi * 1024);
#pragma unroll
        for (int ni = 0; ni < 4; ++ni) bf[ni] = *(const half8*)(cB + ni * 1024);
#pragma unroll
        for (int mi = 0; mi < 4; ++mi)
#pragma unroll
            for (int ni = 0; ni < 4; ++ni)
                acc[mi][ni] = __builtin_amdgcn_mfma_f32_16x16x32_f16(
                    af[mi], bf[ni], acc[mi][ni], 0, 0, 0);
        // k-half 1 (slot ^4 -> byte offset x1)
#pragma unroll
        for (int mi = 0; mi < 4; ++mi) af[mi] = *(const half8*)(cA + mi * 1024 + x1);
#pragma unroll
        for (int ni = 0; ni < 4; ++ni) bf[ni] = *(const half8*)(cB + ni * 1024 + x1);
#pragma unroll
        for (int mi = 0; mi < 4; ++mi)
#pragma unroll
            for (int ni = 0; ni < 4; ++ni)
                acc[mi][ni] = __builtin_amdgcn_mfma_f32_16x16x32_f16(
                    af[mi], bf[ni], acc[mi][ni], 0, 0, 0);
    }

    // epilogue: C/D layout col = lane&15, row = (lane>>4)*4 + reg (m89)
#pragma unroll
    for (int ni = 0; ni < 4; ++ni) {
        const int gn = tileN + wn * 64 + ni * 16 + l16;
        const float bv = bias[gn];
#pragma unroll
        for (int mi = 0; mi < 4; ++mi) {
            const int gm = tileM + wm * 64 + mi * 16 + kq * 4;
#pragma unroll
            for (int r = 0; r < 4; ++r) {
                float v = acc[mi][ni][r] + bv;
                if (RELU) v = v > 0.f ? v : 0.f;
                C[(size_t)(gm + r) * MATN + gn] = (OutT)v;
            }
        }
    }
}

extern "C" void kernel_launch(void* const* d_in, const int* in_sizes, int n_in,
                              void* d_out, int out_size, void* d_ws, size_t ws_size,
                              hipStream_t stream) {
    const float* x  = (const float*)d_in[0];
    const float* W1 = (const float*)d_in[1];
    const float* b1 = (const float*)d_in[2];
    const float* W2 = (const float*)d_in[3];
    const float* b2 = (const float*)d_in[4];
    const float* W3 = (const float*)d_in[5];
    const float* b3 = (const float*)d_in[6];
    float* out = (float*)d_out;

    const size_t MAT = (size_t)MATN * MATN;
    _Float16* xb = (_Float16*)d_ws;                     // 32MB (reused as h2)
    _Float16* wb = (_Float16*)((char*)d_ws + MAT * 2);  // 32MB (per-layer W)
    _Float16* h1 = (_Float16*)((char*)d_ws + MAT * 4);  // 32MB
    _Float16* h2 = xb;

    const int n8 = (int)(MAT / 8);
    dim3 ggrid(MATN / 128, MATN / 128);  // 32x32

    cvt_f16_2<<<dim3(2048, 2), 256, 0, stream>>>(x, xb, W1, wb, n8);
    gemm_bt<true, _Float16><<<ggrid, 256, 0, stream>>>(xb, wb, b1, h1);

    cvt_f16<<<2048, 256, 0, stream>>>(W2, wb, n8);
    gemm_bt<true, _Float16><<<ggrid, 256, 0, stream>>>(h1, wb, b2, h2);

    cvt_f16<<<2048, 256, 0, stream>>>(W3, wb, n8);
    gemm_bt<false, float><<<ggrid, 256, 0, stream>>>(h2, wb, b3, out);
}